// Round 1
// baseline (5279.595 us; speedup 1.0000x reference)
//
#include <hip/hip_runtime.h>
#include <hip/hip_bf16.h>

// ---------------------------------------------------------------------------
// VisionMamba fp32 baseline.
// B=8, L=196 (14x14 patches), D_MODEL=192, D_INNER=384, D_STATE=16, DT_RANK=12,
// DEPTH=24, D_CONV=4.  All fp32.
//
// Pipeline per layer (5 kernels):
//   addln      : residual += h ; hn = LN(residual)
//   gemm_nt    : xz = hn @ in_proj_w^T            (1568x768, K=192)
//   conv_xproj : u = silu(causal dwconv(xin)); xdbl = u@xpw^T; dt = softplus(...)
//   scan_kernel: selective scan -> y = (scan + u*D) * silu(z)
//   gemm_nt    : h = y @ outproj_w^T              (1568x192, K=384)
// ---------------------------------------------------------------------------

#define NTOK   1568   // B * L
#define DMODEL 192
#define DINNER 384
#define DSTATE 16
#define DTRANK 12
#define DEPTH  24
#define LSEQ   196

// ---------------- patch embed ----------------
// one block per token; 192 threads = one output channel each
__global__ __launch_bounds__(192) void patch_embed(
    const float* __restrict__ x, const float* __restrict__ pw,
    const float* __restrict__ pb, float* __restrict__ residual)
{
    __shared__ float patch[768];
    int blk = blockIdx.x;
    int b = blk / LSEQ, l = blk % LSEQ;
    int py = l / 14, px = l % 14;
    int tid = threadIdx.x;
    for (int idx = tid; idx < 768; idx += 192) {
        int ic = idx >> 8, rem = idx & 255, ky = rem >> 4, kx = rem & 15;
        patch[idx] = x[((b * 3 + ic) * 224 + py * 16 + ky) * 224 + px * 16 + kx];
    }
    __syncthreads();
    int c = tid;
    const float4* wr = (const float4*)&pw[c * 768];
    const float4* pr = (const float4*)&patch[0];
    float acc = pb[c];
#pragma unroll 8
    for (int j = 0; j < 192; ++j) {
        float4 w4 = wr[j];
        float4 p4 = pr[j];
        acc += p4.x * w4.x + p4.y * w4.y + p4.z * w4.z + p4.w * w4.w;
    }
    residual[(b * LSEQ + l) * DMODEL + c] = acc;
}

// ---------------- residual add + layernorm ----------------
// one block (64 threads = 1 wave) per token, 3 elems/thread
__global__ __launch_bounds__(64) void addln(
    const float* __restrict__ h, float* __restrict__ residual,
    float* __restrict__ out, const float* __restrict__ w,
    const float* __restrict__ b, int addH)
{
    int t = blockIdx.x;
    int lane = threadIdx.x;
    int base = t * DMODEL;
    float v[3];
#pragma unroll
    for (int i = 0; i < 3; ++i) {
        int c = lane + i * 64;
        float r = residual[base + c];
        if (addH) r += h[base + c];
        v[i] = r;
        residual[base + c] = r;
    }
    float s = v[0] + v[1] + v[2];
#pragma unroll
    for (int o = 32; o >= 1; o >>= 1) s += __shfl_xor(s, o);
    float mean = s * (1.0f / DMODEL);
    float q = 0.f;
#pragma unroll
    for (int i = 0; i < 3; ++i) { float d = v[i] - mean; q += d * d; }
#pragma unroll
    for (int o = 32; o >= 1; o >>= 1) q += __shfl_xor(q, o);
    float rstd = rsqrtf(q * (1.0f / DMODEL) + 1e-5f);
#pragma unroll
    for (int i = 0; i < 3; ++i) {
        int c = lane + i * 64;
        out[base + c] = (v[i] - mean) * rstd * w[c] + b[c];
    }
}

// ---------------- generic fp32 GEMM:  C[M,N] = A[M,K] * W[N,K]^T ----------------
// 64x64 tile, BK=16, 256 threads, 4x4 micro-tile. Requires K%16==0, N%64==0.
#define BM 64
#define BN 64
#define BKK 16
__global__ __launch_bounds__(256) void gemm_nt(
    const float* __restrict__ A, const float* __restrict__ W,
    float* __restrict__ C, int M, int N, int K)
{
    __shared__ float As[BKK][BM + 4];
    __shared__ float Bs[BKK][BN + 4];
    int tid = threadIdx.x;
    int m0 = blockIdx.x * BM, n0 = blockIdx.y * BN;
    int tx = tid & 15, ty = tid >> 4;
    int lr = tid >> 2;          // 0..63
    int lk = (tid & 3) * 4;     // 0,4,8,12
    float acc[4][4] = {};
    for (int k0 = 0; k0 < K; k0 += BKK) {
        {
            int m = m0 + lr;
            float4 v = make_float4(0.f, 0.f, 0.f, 0.f);
            if (m < M) v = *(const float4*)&A[(size_t)m * K + k0 + lk];
            As[lk + 0][lr] = v.x; As[lk + 1][lr] = v.y;
            As[lk + 2][lr] = v.z; As[lk + 3][lr] = v.w;
        }
        {
            int n = n0 + lr;
            float4 v = *(const float4*)&W[(size_t)n * K + k0 + lk];
            Bs[lk + 0][lr] = v.x; Bs[lk + 1][lr] = v.y;
            Bs[lk + 2][lr] = v.z; Bs[lk + 3][lr] = v.w;
        }
        __syncthreads();
#pragma unroll
        for (int k = 0; k < BKK; ++k) {
            float4 a = *(const float4*)&As[k][ty * 4];
            float4 bv = *(const float4*)&Bs[k][tx * 4];
            acc[0][0] += a.x * bv.x; acc[0][1] += a.x * bv.y; acc[0][2] += a.x * bv.z; acc[0][3] += a.x * bv.w;
            acc[1][0] += a.y * bv.x; acc[1][1] += a.y * bv.y; acc[1][2] += a.y * bv.z; acc[1][3] += a.y * bv.w;
            acc[2][0] += a.z * bv.x; acc[2][1] += a.z * bv.y; acc[2][2] += a.z * bv.z; acc[2][3] += a.z * bv.w;
            acc[3][0] += a.w * bv.x; acc[3][1] += a.w * bv.y; acc[3][2] += a.w * bv.z; acc[3][3] += a.w * bv.w;
        }
        __syncthreads();
    }
#pragma unroll
    for (int i = 0; i < 4; ++i) {
        int m = m0 + ty * 4 + i;
        if (m < M) {
            float4 v = make_float4(acc[i][0], acc[i][1], acc[i][2], acc[i][3]);
            *(float4*)&C[(size_t)m * N + n0 + tx * 4] = v;
        }
    }
}

// ---------------- conv + silu + x_proj + dt(softplus) ----------------
// one block per token, 256 threads
__global__ __launch_bounds__(256) void conv_xproj_dt(
    const float* __restrict__ xz, const float* __restrict__ cw,
    const float* __restrict__ cb, const float* __restrict__ xpw,
    const float* __restrict__ dtw, const float* __restrict__ dtb,
    float* __restrict__ u, float* __restrict__ dtg, float* __restrict__ bcg)
{
    __shared__ float su[DINNER];
    __shared__ float sx[44];
    int blk = blockIdx.x;
    int b = blk / LSEQ, l = blk % LSEQ;
    int tid = threadIdx.x;
    // causal depthwise conv (D_CONV=4) + SiLU
    for (int d = tid; d < DINNER; d += 256) {
        float acc = cb[d];
#pragma unroll
        for (int k = 0; k < 4; ++k) {
            int li = l - 3 + k;
            if (li >= 0) acc += xz[(size_t)(b * LSEQ + li) * 768 + d] * cw[d * 4 + k];
        }
        float sig = 1.f / (1.f + __expf(-acc));
        float val = acc * sig;
        su[d] = val;
        u[(size_t)(b * LSEQ + l) * DINNER + d] = val;
    }
    __syncthreads();
    // x_proj: 44 outputs, 4 lanes each over K=384
    if (tid < 176) {
        int e = tid >> 2, p = tid & 3;
        float acc = 0.f;
        const float* wr = &xpw[e * DINNER + p * 96];
        const float* ur = &su[p * 96];
#pragma unroll 8
        for (int j = 0; j < 96; ++j) acc += ur[j] * wr[j];
        acc += __shfl_xor(acc, 1);
        acc += __shfl_xor(acc, 2);
        if (p == 0) sx[e] = acc;
    }
    __syncthreads();
    // dt = softplus(xdbl[:12] @ dtw^T + dtb)
    for (int d = tid; d < DINNER; d += 256) {
        float acc = dtb[d];
#pragma unroll
        for (int r = 0; r < DTRANK; ++r) acc += sx[r] * dtw[d * DTRANK + r];
        float sp = (acc > 20.f) ? acc : log1pf(__expf(acc));
        dtg[(size_t)(b * LSEQ + l) * DINNER + d] = sp;
    }
    // B (16) and C (16)
    if (tid < 32) bcg[(b * LSEQ + l) * 32 + tid] = sx[DTRANK + tid];
}

// ---------------- selective scan + gating ----------------
// grid = 8 * (384/16) = 192 blocks, 256 threads = 16 d-slots x 16 states
__global__ __launch_bounds__(256) void scan_kernel(
    const float* __restrict__ u, const float* __restrict__ dtg,
    const float* __restrict__ bc, const float* __restrict__ xz,
    const float* __restrict__ Alog, const float* __restrict__ Dp,
    float* __restrict__ y)
{
    int b = blockIdx.x / 24;
    int dg = blockIdx.x % 24;
    int tid = threadIdx.x;
    int s = tid & 15, dl = tid >> 4;
    int d = dg * 16 + dl;
    float Ads = -expf(Alog[d * DSTATE + s]);
    float Dd = Dp[d];
    float h = 0.f;
    size_t base = (size_t)b * LSEQ * DINNER + d;
    size_t bcbase = (size_t)b * LSEQ * 32 + s;
    for (int t = 0; t < LSEQ; ++t) {
        float dtv = dtg[base + (size_t)t * DINNER];
        float uv  = u[base + (size_t)t * DINNER];
        float Bv  = bc[bcbase + (size_t)t * 32];
        float Cv  = bc[bcbase + (size_t)t * 32 + 16];
        float dA  = __expf(dtv * Ads);
        h = dA * h + dtv * uv * Bv;
        float p = h * Cv;
        p += __shfl_xor(p, 1);
        p += __shfl_xor(p, 2);
        p += __shfl_xor(p, 4);
        p += __shfl_xor(p, 8);
        if (s == 0) {
            float zv = xz[(size_t)(b * LSEQ + t) * 768 + DINNER + d];
            float sig = 1.f / (1.f + __expf(-zv));
            y[(size_t)(b * LSEQ + t) * DINNER + d] = (p + uv * Dd) * (zv * sig);
        }
    }
}

// ---------------------------------------------------------------------------
extern "C" void kernel_launch(void* const* d_in, const int* in_sizes, int n_in,
                              void* d_out, int out_size, void* d_ws, size_t ws_size,
                              hipStream_t stream)
{
    const float* x         = (const float*)d_in[0];
    const float* pe_w      = (const float*)d_in[1];
    const float* pe_b      = (const float*)d_in[2];
    const float* norm_w    = (const float*)d_in[3];
    const float* norm_b    = (const float*)d_in[4];
    const float* in_proj_w = (const float*)d_in[5];
    const float* conv_w    = (const float*)d_in[6];
    const float* conv_b    = (const float*)d_in[7];
    const float* xproj_w   = (const float*)d_in[8];
    const float* dtproj_w  = (const float*)d_in[9];
    const float* dtproj_b  = (const float*)d_in[10];
    const float* A_log     = (const float*)d_in[11];
    const float* D_param   = (const float*)d_in[12];
    const float* outproj_w = (const float*)d_in[13];
    const float* normf_w   = (const float*)d_in[14];
    const float* normf_b   = (const float*)d_in[15];

    float* ws = (float*)d_ws;
    // workspace layout (floats); total ~3.97M floats = 15.9 MB
    float* residual = ws;                       // 301056
    float* hn       = residual + 301056;        // 301056
    float* hbuf     = hn + 301056;              // 301056
    float* xz       = hbuf + 301056;            // 1204224
    float* ubuf     = xz + 1204224;             // 602112
    float* dtbuf    = ubuf + 602112;            // 602112
    float* ybuf     = dtbuf + 602112;           // 602112
    float* bcbuf    = ybuf + 602112;            // 50176

    patch_embed<<<NTOK, 192, 0, stream>>>(x, pe_w, pe_b, residual);

    for (int i = 0; i < DEPTH; ++i) {
        addln<<<NTOK, 64, 0, stream>>>(hbuf, residual, hn,
                                       norm_w + i * DMODEL, norm_b + i * DMODEL,
                                       i > 0 ? 1 : 0);
        gemm_nt<<<dim3(25, 12), 256, 0, stream>>>(
            hn, in_proj_w + (size_t)i * 768 * DMODEL, xz, NTOK, 768, DMODEL);
        conv_xproj_dt<<<NTOK, 256, 0, stream>>>(
            xz, conv_w + (size_t)i * DINNER * 4, conv_b + (size_t)i * DINNER,
            xproj_w + (size_t)i * 44 * DINNER, dtproj_w + (size_t)i * DINNER * DTRANK,
            dtproj_b + (size_t)i * DINNER, ubuf, dtbuf, bcbuf);
        scan_kernel<<<192, 256, 0, stream>>>(
            ubuf, dtbuf, bcbuf, xz, A_log + (size_t)i * DINNER * DSTATE,
            D_param + (size_t)i * DINNER, ybuf);
        gemm_nt<<<dim3(25, 3), 256, 0, stream>>>(
            ybuf, outproj_w + (size_t)i * DMODEL * DINNER, hbuf, NTOK, DMODEL, DINNER);
    }

    addln<<<NTOK, 64, 0, stream>>>(hbuf, residual, (float*)d_out,
                                   normf_w, normf_b, 1);
}

// Round 2
// 3164.674 us; speedup vs baseline: 1.6683x; 1.6683x over previous
//
#include <hip/hip_runtime.h>
#include <hip/hip_bf16.h>

// ---------------------------------------------------------------------------
// VisionMamba fp32, round 1: LDS-staged selective scan.
// B=8, L=196, D_MODEL=192, D_INNER=384, D_STATE=16, DT_RANK=12, DEPTH=24.
//
// R1 change: scan_kernel was latency-bound (147us/dispatch, VALUBusy 5.7%,
// 1800 cyc/timestep). Now stages 49-timestep chunks of dt/u/z/B/C into LDS
// with coalesced loads; inner loop is VALU+LDS only; y written coalesced.
// ---------------------------------------------------------------------------

#define NTOK   1568   // B * L
#define DMODEL 192
#define DINNER 384
#define DSTATE 16
#define DTRANK 12
#define DEPTH  24
#define LSEQ   196
#define TCH    49     // scan time-chunk (196 = 4*49)

// ---------------- patch embed ----------------
__global__ __launch_bounds__(192) void patch_embed(
    const float* __restrict__ x, const float* __restrict__ pw,
    const float* __restrict__ pb, float* __restrict__ residual)
{
    __shared__ float patch[768];
    int blk = blockIdx.x;
    int b = blk / LSEQ, l = blk % LSEQ;
    int py = l / 14, px = l % 14;
    int tid = threadIdx.x;
    for (int idx = tid; idx < 768; idx += 192) {
        int ic = idx >> 8, rem = idx & 255, ky = rem >> 4, kx = rem & 15;
        patch[idx] = x[((b * 3 + ic) * 224 + py * 16 + ky) * 224 + px * 16 + kx];
    }
    __syncthreads();
    int c = tid;
    const float4* wr = (const float4*)&pw[c * 768];
    const float4* pr = (const float4*)&patch[0];
    float acc = pb[c];
#pragma unroll 8
    for (int j = 0; j < 192; ++j) {
        float4 w4 = wr[j];
        float4 p4 = pr[j];
        acc += p4.x * w4.x + p4.y * w4.y + p4.z * w4.z + p4.w * w4.w;
    }
    residual[(b * LSEQ + l) * DMODEL + c] = acc;
}

// ---------------- residual add + layernorm ----------------
__global__ __launch_bounds__(64) void addln(
    const float* __restrict__ h, float* __restrict__ residual,
    float* __restrict__ out, const float* __restrict__ w,
    const float* __restrict__ b, int addH)
{
    int t = blockIdx.x;
    int lane = threadIdx.x;
    int base = t * DMODEL;
    float v[3];
#pragma unroll
    for (int i = 0; i < 3; ++i) {
        int c = lane + i * 64;
        float r = residual[base + c];
        if (addH) r += h[base + c];
        v[i] = r;
        residual[base + c] = r;
    }
    float s = v[0] + v[1] + v[2];
#pragma unroll
    for (int o = 32; o >= 1; o >>= 1) s += __shfl_xor(s, o);
    float mean = s * (1.0f / DMODEL);
    float q = 0.f;
#pragma unroll
    for (int i = 0; i < 3; ++i) { float d = v[i] - mean; q += d * d; }
#pragma unroll
    for (int o = 32; o >= 1; o >>= 1) q += __shfl_xor(q, o);
    float rstd = rsqrtf(q * (1.0f / DMODEL) + 1e-5f);
#pragma unroll
    for (int i = 0; i < 3; ++i) {
        int c = lane + i * 64;
        out[base + c] = (v[i] - mean) * rstd * w[c] + b[c];
    }
}

// ---------------- generic fp32 GEMM:  C[M,N] = A[M,K] * W[N,K]^T ----------------
#define BM 64
#define BN 64
#define BKK 16
__global__ __launch_bounds__(256) void gemm_nt(
    const float* __restrict__ A, const float* __restrict__ W,
    float* __restrict__ C, int M, int N, int K)
{
    __shared__ float As[BKK][BM + 4];
    __shared__ float Bs[BKK][BN + 4];
    int tid = threadIdx.x;
    int m0 = blockIdx.x * BM, n0 = blockIdx.y * BN;
    int tx = tid & 15, ty = tid >> 4;
    int lr = tid >> 2;          // 0..63
    int lk = (tid & 3) * 4;     // 0,4,8,12
    float acc[4][4] = {};
    for (int k0 = 0; k0 < K; k0 += BKK) {
        {
            int m = m0 + lr;
            float4 v = make_float4(0.f, 0.f, 0.f, 0.f);
            if (m < M) v = *(const float4*)&A[(size_t)m * K + k0 + lk];
            As[lk + 0][lr] = v.x; As[lk + 1][lr] = v.y;
            As[lk + 2][lr] = v.z; As[lk + 3][lr] = v.w;
        }
        {
            int n = n0 + lr;
            float4 v = *(const float4*)&W[(size_t)n * K + k0 + lk];
            Bs[lk + 0][lr] = v.x; Bs[lk + 1][lr] = v.y;
            Bs[lk + 2][lr] = v.z; Bs[lk + 3][lr] = v.w;
        }
        __syncthreads();
#pragma unroll
        for (int k = 0; k < BKK; ++k) {
            float4 a = *(const float4*)&As[k][ty * 4];
            float4 bv = *(const float4*)&Bs[k][tx * 4];
            acc[0][0] += a.x * bv.x; acc[0][1] += a.x * bv.y; acc[0][2] += a.x * bv.z; acc[0][3] += a.x * bv.w;
            acc[1][0] += a.y * bv.x; acc[1][1] += a.y * bv.y; acc[1][2] += a.y * bv.z; acc[1][3] += a.y * bv.w;
            acc[2][0] += a.z * bv.x; acc[2][1] += a.z * bv.y; acc[2][2] += a.z * bv.z; acc[2][3] += a.z * bv.w;
            acc[3][0] += a.w * bv.x; acc[3][1] += a.w * bv.y; acc[3][2] += a.w * bv.z; acc[3][3] += a.w * bv.w;
        }
        __syncthreads();
    }
#pragma unroll
    for (int i = 0; i < 4; ++i) {
        int m = m0 + ty * 4 + i;
        if (m < M) {
            float4 v = make_float4(acc[i][0], acc[i][1], acc[i][2], acc[i][3]);
            *(float4*)&C[(size_t)m * N + n0 + tx * 4] = v;
        }
    }
}

// ---------------- conv + silu + x_proj + dt(softplus) ----------------
__global__ __launch_bounds__(256) void conv_xproj_dt(
    const float* __restrict__ xz, const float* __restrict__ cw,
    const float* __restrict__ cb, const float* __restrict__ xpw,
    const float* __restrict__ dtw, const float* __restrict__ dtb,
    float* __restrict__ u, float* __restrict__ dtg, float* __restrict__ bcg)
{
    __shared__ float su[DINNER];
    __shared__ float sx[44];
    int blk = blockIdx.x;
    int b = blk / LSEQ, l = blk % LSEQ;
    int tid = threadIdx.x;
    for (int d = tid; d < DINNER; d += 256) {
        float acc = cb[d];
#pragma unroll
        for (int k = 0; k < 4; ++k) {
            int li = l - 3 + k;
            if (li >= 0) acc += xz[(size_t)(b * LSEQ + li) * 768 + d] * cw[d * 4 + k];
        }
        float sig = 1.f / (1.f + __expf(-acc));
        float val = acc * sig;
        su[d] = val;
        u[(size_t)(b * LSEQ + l) * DINNER + d] = val;
    }
    __syncthreads();
    if (tid < 176) {
        int e = tid >> 2, p = tid & 3;
        float acc = 0.f;
        const float* wr = &xpw[e * DINNER + p * 96];
        const float* ur = &su[p * 96];
#pragma unroll 8
        for (int j = 0; j < 96; ++j) acc += ur[j] * wr[j];
        acc += __shfl_xor(acc, 1);
        acc += __shfl_xor(acc, 2);
        if (p == 0) sx[e] = acc;
    }
    __syncthreads();
    for (int d = tid; d < DINNER; d += 256) {
        float acc = dtb[d];
#pragma unroll
        for (int r = 0; r < DTRANK; ++r) acc += sx[r] * dtw[d * DTRANK + r];
        float sp = (acc > 20.f) ? acc : log1pf(__expf(acc));
        dtg[(size_t)(b * LSEQ + l) * DINNER + d] = sp;
    }
    if (tid < 32) bcg[(b * LSEQ + l) * 32 + tid] = sx[DTRANK + tid];
}

// ---------------- selective scan + gating (LDS-chunked) ----------------
// grid = 8 * 24 = 192 blocks, 256 threads = 16 d-slots x 16 states.
// Stages TCH timesteps of dt/u/z (16 d each) + B/C (16 s each) into LDS,
// runs the recurrence from LDS, stages y in LDS, writes coalesced.
__global__ __launch_bounds__(256) void scan_kernel(
    const float* __restrict__ u, const float* __restrict__ dtg,
    const float* __restrict__ bc, const float* __restrict__ xz,
    const float* __restrict__ Alog, const float* __restrict__ Dp,
    float* __restrict__ y)
{
    __shared__ float sdt[TCH][16];
    __shared__ float su_[TCH][16];
    __shared__ float sz_[TCH][16];
    __shared__ float sB_[TCH][16];
    __shared__ float sC_[TCH][16];
    __shared__ float sy_[TCH][16];

    int b  = blockIdx.x / 24;
    int dg = blockIdx.x % 24;
    int tid = threadIdx.x;
    int s = tid & 15, dl = tid >> 4;
    int d = dg * 16 + dl;
    float Ads = -expf(Alog[d * DSTATE + s]);
    float Dd  = Dp[d];
    float h = 0.f;

    for (int c0 = 0; c0 < LSEQ; c0 += TCH) {
        // cooperative staging: 784 elements per array, coalesced 16-float rows
        for (int i = tid; i < TCH * 16; i += 256) {
            int t = i >> 4, j = i & 15;
            size_t tok = (size_t)(b * LSEQ + c0 + t);
            sdt[t][j] = dtg[tok * DINNER + dg * 16 + j];
            su_[t][j] = u  [tok * DINNER + dg * 16 + j];
            sz_[t][j] = xz [tok * 768 + DINNER + dg * 16 + j];
            sB_[t][j] = bc [tok * 32 + j];
            sC_[t][j] = bc [tok * 32 + 16 + j];
        }
        __syncthreads();

        for (int t = 0; t < TCH; ++t) {
            float dtv = sdt[t][dl];      // broadcast across s lanes
            float uv  = su_[t][dl];      // broadcast
            float Bv  = sB_[t][s];       // 16 banks, <=2-way (free)
            float Cv  = sC_[t][s];
            float dA  = __expf(dtv * Ads);
            h = dA * h + dtv * uv * Bv;
            float p = h * Cv;
            p += __shfl_xor(p, 1);
            p += __shfl_xor(p, 2);
            p += __shfl_xor(p, 4);
            p += __shfl_xor(p, 8);
            if (s == 0) {
                float zv = sz_[t][dl];
                float sig = 1.f / (1.f + __expf(-zv));
                sy_[t][dl] = (p + uv * Dd) * (zv * sig);
            }
        }
        __syncthreads();

        for (int i = tid; i < TCH * 16; i += 256) {
            int t = i >> 4, j = i & 15;
            y[(size_t)(b * LSEQ + c0 + t) * DINNER + dg * 16 + j] = sy_[t][j];
        }
        __syncthreads();
    }
}

// ---------------------------------------------------------------------------
extern "C" void kernel_launch(void* const* d_in, const int* in_sizes, int n_in,
                              void* d_out, int out_size, void* d_ws, size_t ws_size,
                              hipStream_t stream)
{
    const float* x         = (const float*)d_in[0];
    const float* pe_w      = (const float*)d_in[1];
    const float* pe_b      = (const float*)d_in[2];
    const float* norm_w    = (const float*)d_in[3];
    const float* norm_b    = (const float*)d_in[4];
    const float* in_proj_w = (const float*)d_in[5];
    const float* conv_w    = (const float*)d_in[6];
    const float* conv_b    = (const float*)d_in[7];
    const float* xproj_w   = (const float*)d_in[8];
    const float* dtproj_w  = (const float*)d_in[9];
    const float* dtproj_b  = (const float*)d_in[10];
    const float* A_log     = (const float*)d_in[11];
    const float* D_param   = (const float*)d_in[12];
    const float* outproj_w = (const float*)d_in[13];
    const float* normf_w   = (const float*)d_in[14];
    const float* normf_b   = (const float*)d_in[15];

    float* ws = (float*)d_ws;
    float* residual = ws;                       // 301056
    float* hn       = residual + 301056;        // 301056
    float* hbuf     = hn + 301056;              // 301056
    float* xz       = hbuf + 301056;            // 1204224
    float* ubuf     = xz + 1204224;             // 602112
    float* dtbuf    = ubuf + 602112;            // 602112
    float* ybuf     = dtbuf + 602112;           // 602112
    float* bcbuf    = ybuf + 602112;            // 50176

    patch_embed<<<NTOK, 192, 0, stream>>>(x, pe_w, pe_b, residual);

    for (int i = 0; i < DEPTH; ++i) {
        addln<<<NTOK, 64, 0, stream>>>(hbuf, residual, hn,
                                       norm_w + i * DMODEL, norm_b + i * DMODEL,
                                       i > 0 ? 1 : 0);
        gemm_nt<<<dim3(25, 12), 256, 0, stream>>>(
            hn, in_proj_w + (size_t)i * 768 * DMODEL, xz, NTOK, 768, DMODEL);
        conv_xproj_dt<<<NTOK, 256, 0, stream>>>(
            xz, conv_w + (size_t)i * DINNER * 4, conv_b + (size_t)i * DINNER,
            xproj_w + (size_t)i * 44 * DINNER, dtproj_w + (size_t)i * DINNER * DTRANK,
            dtproj_b + (size_t)i * DINNER, ubuf, dtbuf, bcbuf);
        scan_kernel<<<192, 256, 0, stream>>>(
            ubuf, dtbuf, bcbuf, xz, A_log + (size_t)i * DINNER * DSTATE,
            D_param + (size_t)i * DINNER, ybuf);
        gemm_nt<<<dim3(25, 3), 256, 0, stream>>>(
            ybuf, outproj_w + (size_t)i * DMODEL * DINNER, hbuf, NTOK, DMODEL, DINNER);
    }

    addln<<<NTOK, 64, 0, stream>>>(hbuf, residual, (float*)d_out,
                                   normf_w, normf_b, 1);
}

// Round 3
// 2673.791 us; speedup vs baseline: 1.9746x; 1.1836x over previous
//
#include <hip/hip_runtime.h>
#include <hip/hip_bf16.h>

// ---------------------------------------------------------------------------
// VisionMamba, round 2: bf16-MFMA GEMMs.
// B=8, L=196, D_MODEL=192, D_INNER=384, D_STATE=16, DT_RANK=12, DEPTH=24.
//
// R2 change: all three GEMMs (patch-embed via im2col, in_proj, out_proj) use
// v_mfma_f32_16x16x32_bf16 with fp32->bf16 conversion fused into LDS staging.
// Verified layouts: A[m=lane&15][k=quad*8+j]; C/D col=lane&15, row=quad*4+reg.
// LDS stride 40 bf16 (80B) -> uniform bank spread for b128 fragment reads.
// ---------------------------------------------------------------------------

#define NTOK   1568   // B * L
#define DMODEL 192
#define DINNER 384
#define DSTATE 16
#define DTRANK 12
#define DEPTH  24
#define LSEQ   196
#define TCH    49     // scan time-chunk (196 = 4*49)

typedef __attribute__((ext_vector_type(8))) short short8;
typedef __attribute__((ext_vector_type(4))) float floatx4;

__device__ inline short f2bf(float f) {
    __hip_bfloat16 h = __float2bfloat16(f);
    return *reinterpret_cast<short*>(&h);
}

// ---------------- im2col for patch embed ----------------
// patches[tok][e] with e = (ic,ky,kx) ordering matching pe_w rows
__global__ __launch_bounds__(256) void im2col(
    const float* __restrict__ x, float* __restrict__ patches)
{
    int idx = blockIdx.x * 256 + threadIdx.x;
    if (idx >= NTOK * 768) return;
    int tok = idx / 768, e = idx % 768;
    int b = tok / LSEQ, l = tok % LSEQ;
    int py = l / 14, px = l % 14;
    int ic = e >> 8, rem = e & 255, ky = rem >> 4, kx = rem & 15;
    patches[idx] = x[((b * 3 + ic) * 224 + py * 16 + ky) * 224 + px * 16 + kx];
}

// ---------------- bf16 MFMA GEMM:  C[M,N] = A[M,K] * W[N,K]^T (+bias) ----------------
// 64x64 tile, BK=32, 256 threads = 4 waves; wave w computes rows [w*16,w*16+16)
// x 64 cols (4 MFMA tiles). fp32 inputs converted to bf16 during LDS staging.
#define LDA 40   // LDS row stride in bf16 elements (80B): uniform bank spread
__global__ __launch_bounds__(256) void gemm_bf16(
    const float* __restrict__ A, const float* __restrict__ W,
    const float* __restrict__ bias, float* __restrict__ C,
    int M, int N, int K)
{
    __shared__ short As[64 * LDA];
    __shared__ short Ws[64 * LDA];
    int tid = threadIdx.x;
    int m0 = blockIdx.x * 64, n0 = blockIdx.y * 64;
    int wv = tid >> 6, lane = tid & 63;
    int fm = lane & 15, q = lane >> 4;
    int row = tid >> 2, kc = (tid & 3) * 8;   // staging: 64 rows x 32 k
    floatx4 acc[4] = {{0.f,0.f,0.f,0.f},{0.f,0.f,0.f,0.f},{0.f,0.f,0.f,0.f},{0.f,0.f,0.f,0.f}};

    for (int k0 = 0; k0 < K; k0 += 32) {
        {
            int m = m0 + row;
            float4 a0 = make_float4(0.f,0.f,0.f,0.f), a1 = a0;
            if (m < M) {
                a0 = *(const float4*)&A[(size_t)m * K + k0 + kc];
                a1 = *(const float4*)&A[(size_t)m * K + k0 + kc + 4];
            }
            short8 v;
            v[0]=f2bf(a0.x); v[1]=f2bf(a0.y); v[2]=f2bf(a0.z); v[3]=f2bf(a0.w);
            v[4]=f2bf(a1.x); v[5]=f2bf(a1.y); v[6]=f2bf(a1.z); v[7]=f2bf(a1.w);
            *(short8*)&As[row * LDA + kc] = v;
        }
        {
            int n = n0 + row;   // grid guarantees n < N
            float4 b0 = *(const float4*)&W[(size_t)n * K + k0 + kc];
            float4 b1 = *(const float4*)&W[(size_t)n * K + k0 + kc + 4];
            short8 v;
            v[0]=f2bf(b0.x); v[1]=f2bf(b0.y); v[2]=f2bf(b0.z); v[3]=f2bf(b0.w);
            v[4]=f2bf(b1.x); v[5]=f2bf(b1.y); v[6]=f2bf(b1.z); v[7]=f2bf(b1.w);
            *(short8*)&Ws[row * LDA + kc] = v;
        }
        __syncthreads();
        short8 af = *(const short8*)&As[(wv * 16 + fm) * LDA + q * 8];
#pragma unroll
        for (int nt = 0; nt < 4; ++nt) {
            short8 bf = *(const short8*)&Ws[(nt * 16 + fm) * LDA + q * 8];
            acc[nt] = __builtin_amdgcn_mfma_f32_16x16x32_bf16(af, bf, acc[nt], 0, 0, 0);
        }
        __syncthreads();
    }
#pragma unroll
    for (int nt = 0; nt < 4; ++nt) {
        int col = n0 + nt * 16 + fm;
        float bv = bias ? bias[col] : 0.f;
#pragma unroll
        for (int r = 0; r < 4; ++r) {
            int mrow = m0 + wv * 16 + q * 4 + r;
            if (mrow < M) C[(size_t)mrow * N + col] = acc[nt][r] + bv;
        }
    }
}

// ---------------- residual add + layernorm ----------------
__global__ __launch_bounds__(64) void addln(
    const float* __restrict__ h, float* __restrict__ residual,
    float* __restrict__ out, const float* __restrict__ w,
    const float* __restrict__ b, int addH)
{
    int t = blockIdx.x;
    int lane = threadIdx.x;
    int base = t * DMODEL;
    float v[3];
#pragma unroll
    for (int i = 0; i < 3; ++i) {
        int c = lane + i * 64;
        float r = residual[base + c];
        if (addH) r += h[base + c];
        v[i] = r;
        residual[base + c] = r;
    }
    float s = v[0] + v[1] + v[2];
#pragma unroll
    for (int o = 32; o >= 1; o >>= 1) s += __shfl_xor(s, o);
    float mean = s * (1.0f / DMODEL);
    float q = 0.f;
#pragma unroll
    for (int i = 0; i < 3; ++i) { float d = v[i] - mean; q += d * d; }
#pragma unroll
    for (int o = 32; o >= 1; o >>= 1) q += __shfl_xor(q, o);
    float rstd = rsqrtf(q * (1.0f / DMODEL) + 1e-5f);
#pragma unroll
    for (int i = 0; i < 3; ++i) {
        int c = lane + i * 64;
        out[base + c] = (v[i] - mean) * rstd * w[c] + b[c];
    }
}

// ---------------- conv + silu + x_proj + dt(softplus) ----------------
__global__ __launch_bounds__(256) void conv_xproj_dt(
    const float* __restrict__ xz, const float* __restrict__ cw,
    const float* __restrict__ cb, const float* __restrict__ xpw,
    const float* __restrict__ dtw, const float* __restrict__ dtb,
    float* __restrict__ u, float* __restrict__ dtg, float* __restrict__ bcg)
{
    __shared__ float su[DINNER];
    __shared__ float sx[44];
    int blk = blockIdx.x;
    int b = blk / LSEQ, l = blk % LSEQ;
    int tid = threadIdx.x;
    for (int d = tid; d < DINNER; d += 256) {
        float acc = cb[d];
#pragma unroll
        for (int k = 0; k < 4; ++k) {
            int li = l - 3 + k;
            if (li >= 0) acc += xz[(size_t)(b * LSEQ + li) * 768 + d] * cw[d * 4 + k];
        }
        float sig = 1.f / (1.f + __expf(-acc));
        float val = acc * sig;
        su[d] = val;
        u[(size_t)(b * LSEQ + l) * DINNER + d] = val;
    }
    __syncthreads();
    if (tid < 176) {
        int e = tid >> 2, p = tid & 3;
        float acc = 0.f;
        const float* wr = &xpw[e * DINNER + p * 96];
        const float* ur = &su[p * 96];
#pragma unroll 8
        for (int j = 0; j < 96; ++j) acc += ur[j] * wr[j];
        acc += __shfl_xor(acc, 1);
        acc += __shfl_xor(acc, 2);
        if (p == 0) sx[e] = acc;
    }
    __syncthreads();
    for (int d = tid; d < DINNER; d += 256) {
        float acc = dtb[d];
#pragma unroll
        for (int r = 0; r < DTRANK; ++r) acc += sx[r] * dtw[d * DTRANK + r];
        float sp = (acc > 20.f) ? acc : log1pf(__expf(acc));
        dtg[(size_t)(b * LSEQ + l) * DINNER + d] = sp;
    }
    if (tid < 32) bcg[(b * LSEQ + l) * 32 + tid] = sx[DTRANK + tid];
}

// ---------------- selective scan + gating (LDS-chunked) ----------------
__global__ __launch_bounds__(256) void scan_kernel(
    const float* __restrict__ u, const float* __restrict__ dtg,
    const float* __restrict__ bc, const float* __restrict__ xz,
    const float* __restrict__ Alog, const float* __restrict__ Dp,
    float* __restrict__ y)
{
    __shared__ float sdt[TCH][16];
    __shared__ float su_[TCH][16];
    __shared__ float sz_[TCH][16];
    __shared__ float sB_[TCH][16];
    __shared__ float sC_[TCH][16];
    __shared__ float sy_[TCH][16];

    int b  = blockIdx.x / 24;
    int dg = blockIdx.x % 24;
    int tid = threadIdx.x;
    int s = tid & 15, dl = tid >> 4;
    int d = dg * 16 + dl;
    float Ads = -expf(Alog[d * DSTATE + s]);
    float Dd  = Dp[d];
    float h = 0.f;

    for (int c0 = 0; c0 < LSEQ; c0 += TCH) {
        for (int i = tid; i < TCH * 16; i += 256) {
            int t = i >> 4, j = i & 15;
            size_t tok = (size_t)(b * LSEQ + c0 + t);
            sdt[t][j] = dtg[tok * DINNER + dg * 16 + j];
            su_[t][j] = u  [tok * DINNER + dg * 16 + j];
            sz_[t][j] = xz [tok * 768 + DINNER + dg * 16 + j];
            sB_[t][j] = bc [tok * 32 + j];
            sC_[t][j] = bc [tok * 32 + 16 + j];
        }
        __syncthreads();

        for (int t = 0; t < TCH; ++t) {
            float dtv = sdt[t][dl];
            float uv  = su_[t][dl];
            float Bv  = sB_[t][s];
            float Cv  = sC_[t][s];
            float dA  = __expf(dtv * Ads);
            h = dA * h + dtv * uv * Bv;
            float p = h * Cv;
            p += __shfl_xor(p, 1);
            p += __shfl_xor(p, 2);
            p += __shfl_xor(p, 4);
            p += __shfl_xor(p, 8);
            if (s == 0) {
                float zv = sz_[t][dl];
                float sig = 1.f / (1.f + __expf(-zv));
                sy_[t][dl] = (p + uv * Dd) * (zv * sig);
            }
        }
        __syncthreads();

        for (int i = tid; i < TCH * 16; i += 256) {
            int t = i >> 4, j = i & 15;
            y[(size_t)(b * LSEQ + c0 + t) * DINNER + dg * 16 + j] = sy_[t][j];
        }
        __syncthreads();
    }
}

// ---------------------------------------------------------------------------
extern "C" void kernel_launch(void* const* d_in, const int* in_sizes, int n_in,
                              void* d_out, int out_size, void* d_ws, size_t ws_size,
                              hipStream_t stream)
{
    const float* x         = (const float*)d_in[0];
    const float* pe_w      = (const float*)d_in[1];
    const float* pe_b      = (const float*)d_in[2];
    const float* norm_w    = (const float*)d_in[3];
    const float* norm_b    = (const float*)d_in[4];
    const float* in_proj_w = (const float*)d_in[5];
    const float* conv_w    = (const float*)d_in[6];
    const float* conv_b    = (const float*)d_in[7];
    const float* xproj_w   = (const float*)d_in[8];
    const float* dtproj_w  = (const float*)d_in[9];
    const float* dtproj_b  = (const float*)d_in[10];
    const float* A_log     = (const float*)d_in[11];
    const float* D_param   = (const float*)d_in[12];
    const float* outproj_w = (const float*)d_in[13];
    const float* normf_w   = (const float*)d_in[14];
    const float* normf_b   = (const float*)d_in[15];

    float* ws = (float*)d_ws;
    float* residual = ws;                       // 301056
    float* hn       = residual + 301056;        // 301056
    float* hbuf     = hn + 301056;              // 301056
    float* xz       = hbuf + 301056;            // 1204224
    float* ubuf     = xz + 1204224;             // 602112
    float* dtbuf    = ubuf + 602112;            // 602112
    float* ybuf     = dtbuf + 602112;           // 602112
    float* bcbuf    = ybuf + 602112;            // 50176
    // patches aliases ubuf+dtbuf (1204224 floats), only used before layer loop
    float* patches  = ubuf;

    im2col<<<(NTOK * 768 + 255) / 256, 256, 0, stream>>>(x, patches);
    gemm_bf16<<<dim3(25, 3), 256, 0, stream>>>(
        patches, pe_w, pe_b, residual, NTOK, DMODEL, 768);

    for (int i = 0; i < DEPTH; ++i) {
        addln<<<NTOK, 64, 0, stream>>>(hbuf, residual, hn,
                                       norm_w + i * DMODEL, norm_b + i * DMODEL,
                                       i > 0 ? 1 : 0);
        gemm_bf16<<<dim3(25, 12), 256, 0, stream>>>(
            hn, in_proj_w + (size_t)i * 768 * DMODEL, nullptr, xz, NTOK, 768, DMODEL);
        conv_xproj_dt<<<NTOK, 256, 0, stream>>>(
            xz, conv_w + (size_t)i * DINNER * 4, conv_b + (size_t)i * DINNER,
            xproj_w + (size_t)i * 44 * DINNER, dtproj_w + (size_t)i * DINNER * DTRANK,
            dtproj_b + (size_t)i * DINNER, ubuf, dtbuf, bcbuf);
        scan_kernel<<<192, 256, 0, stream>>>(
            ubuf, dtbuf, bcbuf, xz, A_log + (size_t)i * DINNER * DSTATE,
            D_param + (size_t)i * DINNER, ybuf);
        gemm_bf16<<<dim3(25, 3), 256, 0, stream>>>(
            ybuf, outproj_w + (size_t)i * DMODEL * DINNER, nullptr, hbuf, NTOK, DMODEL, DINNER);
    }

    addln<<<NTOK, 64, 0, stream>>>(hbuf, residual, (float*)d_out,
                                   normf_w, normf_b, 1);
}

// Round 4
// 1672.239 us; speedup vs baseline: 3.1572x; 1.5989x over previous
//
#include <hip/hip_runtime.h>
#include <hip/hip_bf16.h>

// ---------------------------------------------------------------------------
// VisionMamba, round 3: latency-free selective scan.
// B=8, L=196, D_MODEL=192, D_INNER=384, D_STATE=16, DT_RANK=12, DEPTH=24.
//
// R3 change: scan_kernel recurrence had 725 cyc/step (4 dependent shfl_xor +
// unpipelined LDS latency exposed at 1 wave/SIMD). New structure per chunk:
//   phase 1: float4 staging of dt/u/z/B/C into LDS
//   phase 2: recurrence, NO shuffles/divergence; per-state product h*C written
//            to sprod[t][dl*17+s] (pad-17: <=2-way banks = free)
//   phase 3: reduce 16 states + u*D + silu(z) gate, coalesced y writes
// Loop-carried chain is only h=dA*h+dBu (4cyc fma); all loads prefetchable.
// ---------------------------------------------------------------------------

#define NTOK   1568   // B * L
#define DMODEL 192
#define DINNER 384
#define DSTATE 16
#define DTRANK 12
#define DEPTH  24
#define LSEQ   196
#define TCH    49     // scan time-chunk (196 = 4*49)

typedef __attribute__((ext_vector_type(8))) short short8;
typedef __attribute__((ext_vector_type(4))) float floatx4;

__device__ inline short f2bf(float f) {
    __hip_bfloat16 h = __float2bfloat16(f);
    return *reinterpret_cast<short*>(&h);
}

// ---------------- im2col for patch embed ----------------
__global__ __launch_bounds__(256) void im2col(
    const float* __restrict__ x, float* __restrict__ patches)
{
    int idx = blockIdx.x * 256 + threadIdx.x;
    if (idx >= NTOK * 768) return;
    int tok = idx / 768, e = idx % 768;
    int b = tok / LSEQ, l = tok % LSEQ;
    int py = l / 14, px = l % 14;
    int ic = e >> 8, rem = e & 255, ky = rem >> 4, kx = rem & 15;
    patches[idx] = x[((b * 3 + ic) * 224 + py * 16 + ky) * 224 + px * 16 + kx];
}

// ---------------- bf16 MFMA GEMM:  C[M,N] = A[M,K] * W[N,K]^T (+bias) ----------------
#define LDA 40   // LDS row stride in bf16 elements (80B): uniform bank spread
__global__ __launch_bounds__(256) void gemm_bf16(
    const float* __restrict__ A, const float* __restrict__ W,
    const float* __restrict__ bias, float* __restrict__ C,
    int M, int N, int K)
{
    __shared__ short As[64 * LDA];
    __shared__ short Ws[64 * LDA];
    int tid = threadIdx.x;
    int m0 = blockIdx.x * 64, n0 = blockIdx.y * 64;
    int wv = tid >> 6, lane = tid & 63;
    int fm = lane & 15, q = lane >> 4;
    int row = tid >> 2, kc = (tid & 3) * 8;
    floatx4 acc[4] = {{0.f,0.f,0.f,0.f},{0.f,0.f,0.f,0.f},{0.f,0.f,0.f,0.f},{0.f,0.f,0.f,0.f}};

    for (int k0 = 0; k0 < K; k0 += 32) {
        {
            int m = m0 + row;
            float4 a0 = make_float4(0.f,0.f,0.f,0.f), a1 = a0;
            if (m < M) {
                a0 = *(const float4*)&A[(size_t)m * K + k0 + kc];
                a1 = *(const float4*)&A[(size_t)m * K + k0 + kc + 4];
            }
            short8 v;
            v[0]=f2bf(a0.x); v[1]=f2bf(a0.y); v[2]=f2bf(a0.z); v[3]=f2bf(a0.w);
            v[4]=f2bf(a1.x); v[5]=f2bf(a1.y); v[6]=f2bf(a1.z); v[7]=f2bf(a1.w);
            *(short8*)&As[row * LDA + kc] = v;
        }
        {
            int n = n0 + row;
            float4 b0 = *(const float4*)&W[(size_t)n * K + k0 + kc];
            float4 b1 = *(const float4*)&W[(size_t)n * K + k0 + kc + 4];
            short8 v;
            v[0]=f2bf(b0.x); v[1]=f2bf(b0.y); v[2]=f2bf(b0.z); v[3]=f2bf(b0.w);
            v[4]=f2bf(b1.x); v[5]=f2bf(b1.y); v[6]=f2bf(b1.z); v[7]=f2bf(b1.w);
            *(short8*)&Ws[row * LDA + kc] = v;
        }
        __syncthreads();
        short8 af = *(const short8*)&As[(wv * 16 + fm) * LDA + q * 8];
#pragma unroll
        for (int nt = 0; nt < 4; ++nt) {
            short8 bf = *(const short8*)&Ws[(nt * 16 + fm) * LDA + q * 8];
            acc[nt] = __builtin_amdgcn_mfma_f32_16x16x32_bf16(af, bf, acc[nt], 0, 0, 0);
        }
        __syncthreads();
    }
#pragma unroll
    for (int nt = 0; nt < 4; ++nt) {
        int col = n0 + nt * 16 + fm;
        float bv = bias ? bias[col] : 0.f;
#pragma unroll
        for (int r = 0; r < 4; ++r) {
            int mrow = m0 + wv * 16 + q * 4 + r;
            if (mrow < M) C[(size_t)mrow * N + col] = acc[nt][r] + bv;
        }
    }
}

// ---------------- residual add + layernorm ----------------
__global__ __launch_bounds__(64) void addln(
    const float* __restrict__ h, float* __restrict__ residual,
    float* __restrict__ out, const float* __restrict__ w,
    const float* __restrict__ b, int addH)
{
    int t = blockIdx.x;
    int lane = threadIdx.x;
    int base = t * DMODEL;
    float v[3];
#pragma unroll
    for (int i = 0; i < 3; ++i) {
        int c = lane + i * 64;
        float r = residual[base + c];
        if (addH) r += h[base + c];
        v[i] = r;
        residual[base + c] = r;
    }
    float s = v[0] + v[1] + v[2];
#pragma unroll
    for (int o = 32; o >= 1; o >>= 1) s += __shfl_xor(s, o);
    float mean = s * (1.0f / DMODEL);
    float q = 0.f;
#pragma unroll
    for (int i = 0; i < 3; ++i) { float d = v[i] - mean; q += d * d; }
#pragma unroll
    for (int o = 32; o >= 1; o >>= 1) q += __shfl_xor(q, o);
    float rstd = rsqrtf(q * (1.0f / DMODEL) + 1e-5f);
#pragma unroll
    for (int i = 0; i < 3; ++i) {
        int c = lane + i * 64;
        out[base + c] = (v[i] - mean) * rstd * w[c] + b[c];
    }
}

// ---------------- conv + silu + x_proj + dt(softplus) ----------------
__global__ __launch_bounds__(256) void conv_xproj_dt(
    const float* __restrict__ xz, const float* __restrict__ cw,
    const float* __restrict__ cb, const float* __restrict__ xpw,
    const float* __restrict__ dtw, const float* __restrict__ dtb,
    float* __restrict__ u, float* __restrict__ dtg, float* __restrict__ bcg)
{
    __shared__ float su[DINNER];
    __shared__ float sx[44];
    int blk = blockIdx.x;
    int b = blk / LSEQ, l = blk % LSEQ;
    int tid = threadIdx.x;
    for (int d = tid; d < DINNER; d += 256) {
        float acc = cb[d];
#pragma unroll
        for (int k = 0; k < 4; ++k) {
            int li = l - 3 + k;
            if (li >= 0) acc += xz[(size_t)(b * LSEQ + li) * 768 + d] * cw[d * 4 + k];
        }
        float sig = 1.f / (1.f + __expf(-acc));
        float val = acc * sig;
        su[d] = val;
        u[(size_t)(b * LSEQ + l) * DINNER + d] = val;
    }
    __syncthreads();
    if (tid < 176) {
        int e = tid >> 2, p = tid & 3;
        float acc = 0.f;
        const float* wr = &xpw[e * DINNER + p * 96];
        const float* ur = &su[p * 96];
#pragma unroll 8
        for (int j = 0; j < 96; ++j) acc += ur[j] * wr[j];
        acc += __shfl_xor(acc, 1);
        acc += __shfl_xor(acc, 2);
        if (p == 0) sx[e] = acc;
    }
    __syncthreads();
    for (int d = tid; d < DINNER; d += 256) {
        float acc = dtb[d];
#pragma unroll
        for (int r = 0; r < DTRANK; ++r) acc += sx[r] * dtw[d * DTRANK + r];
        float sp = (acc > 20.f) ? acc : log1pf(__expf(acc));
        dtg[(size_t)(b * LSEQ + l) * DINNER + d] = sp;
    }
    if (tid < 32) bcg[(b * LSEQ + l) * 32 + tid] = sx[DTRANK + tid];
}

// ---------------- selective scan + gating (3-phase, latency-free) ----------------
// grid = 8*24 blocks; 256 threads. Recurrence: thread (s=tid&15, dl=tid>>4)
// owns state s of channel dl. Products to sprod[t][dl*17+s]; reduce pass sums
// 16 states per (t,dl), applies u*D + silu(z) gate, writes y coalesced.
#define SPAD 272   // sprod row stride (floats); dl*17+s max 270
__global__ __launch_bounds__(256) void scan_kernel(
    const float* __restrict__ u, const float* __restrict__ dtg,
    const float* __restrict__ bc, const float* __restrict__ xz,
    const float* __restrict__ Alog, const float* __restrict__ Dp,
    float* __restrict__ y)
{
    __shared__ float sdt[TCH][16];
    __shared__ float su_[TCH][16];
    __shared__ float sz_[TCH][16];
    __shared__ float sB_[TCH][16];
    __shared__ float sC_[TCH][16];
    __shared__ float sprod[TCH][SPAD];

    int b  = blockIdx.x / 24;
    int dg = blockIdx.x % 24;
    int tid = threadIdx.x;
    int s = tid & 15, dl = tid >> 4;
    int d = dg * 16 + dl;
    float Ads = -expf(Alog[d * DSTATE + s]);
    float Dd2 = Dp[dg * 16 + (tid & 15)];   // for reduce phase (dl2 = tid&15)
    float h = 0.f;

    for (int c0 = 0; c0 < LSEQ; c0 += TCH) {
        // ---- phase 1: float4 staging (196 work items, one per (t, j4)) ----
        if (tid < TCH * 4) {
            int t = tid >> 2, j4 = (tid & 3) * 4;
            size_t tok = (size_t)(b * LSEQ + c0 + t);
            *(float4*)&sdt[t][j4] = *(const float4*)&dtg[tok * DINNER + dg * 16 + j4];
            *(float4*)&su_[t][j4] = *(const float4*)&u  [tok * DINNER + dg * 16 + j4];
            *(float4*)&sz_[t][j4] = *(const float4*)&xz [tok * 768 + DINNER + dg * 16 + j4];
            *(float4*)&sB_[t][j4] = *(const float4*)&bc [tok * 32 + j4];
            *(float4*)&sC_[t][j4] = *(const float4*)&bc [tok * 32 + 16 + j4];
        }
        __syncthreads();

        // ---- phase 2: recurrence (no shuffles, no divergence, no barrier) ----
#pragma unroll 7
        for (int t = 0; t < TCH; ++t) {
            float dtv = sdt[t][dl];      // broadcast across s lanes
            float uv  = su_[t][dl];      // broadcast
            float Bv  = sB_[t][s];       // 16 distinct banks, broadcast over dl
            float Cv  = sC_[t][s];
            float dA  = __expf(dtv * Ads);
            h = dA * h + (dtv * uv) * Bv;
            sprod[t][dl * 17 + s] = h * Cv;
        }
        __syncthreads();

        // ---- phase 3: reduce 16 states + gate + coalesced store ----
        for (int i = tid; i < TCH * 16; i += 256) {
            int t = i >> 4, dl2 = i & 15;
            float sum = 0.f;
#pragma unroll
            for (int j = 0; j < 16; ++j) sum += sprod[t][dl2 * 17 + j];
            float uv = su_[t][dl2];
            float zv = sz_[t][dl2];
            float sig = 1.f / (1.f + __expf(-zv));
            y[(size_t)(b * LSEQ + c0 + t) * DINNER + dg * 16 + dl2] =
                (sum + uv * Dd2) * (zv * sig);
        }
        __syncthreads();
    }
}

// ---------------------------------------------------------------------------
extern "C" void kernel_launch(void* const* d_in, const int* in_sizes, int n_in,
                              void* d_out, int out_size, void* d_ws, size_t ws_size,
                              hipStream_t stream)
{
    const float* x         = (const float*)d_in[0];
    const float* pe_w      = (const float*)d_in[1];
    const float* pe_b      = (const float*)d_in[2];
    const float* norm_w    = (const float*)d_in[3];
    const float* norm_b    = (const float*)d_in[4];
    const float* in_proj_w = (const float*)d_in[5];
    const float* conv_w    = (const float*)d_in[6];
    const float* conv_b    = (const float*)d_in[7];
    const float* xproj_w   = (const float*)d_in[8];
    const float* dtproj_w  = (const float*)d_in[9];
    const float* dtproj_b  = (const float*)d_in[10];
    const float* A_log     = (const float*)d_in[11];
    const float* D_param   = (const float*)d_in[12];
    const float* outproj_w = (const float*)d_in[13];
    const float* normf_w   = (const float*)d_in[14];
    const float* normf_b   = (const float*)d_in[15];

    float* ws = (float*)d_ws;
    float* residual = ws;                       // 301056
    float* hn       = residual + 301056;        // 301056
    float* hbuf     = hn + 301056;              // 301056
    float* xz       = hbuf + 301056;            // 1204224
    float* ubuf     = xz + 1204224;             // 602112
    float* dtbuf    = ubuf + 602112;            // 602112
    float* ybuf     = dtbuf + 602112;           // 602112
    float* bcbuf    = ybuf + 602112;            // 50176
    float* patches  = ubuf;   // aliases ubuf+dtbuf, used only before layer loop

    im2col<<<(NTOK * 768 + 255) / 256, 256, 0, stream>>>(x, patches);
    gemm_bf16<<<dim3(25, 3), 256, 0, stream>>>(
        patches, pe_w, pe_b, residual, NTOK, DMODEL, 768);

    for (int i = 0; i < DEPTH; ++i) {
        addln<<<NTOK, 64, 0, stream>>>(hbuf, residual, hn,
                                       norm_w + i * DMODEL, norm_b + i * DMODEL,
                                       i > 0 ? 1 : 0);
        gemm_bf16<<<dim3(25, 12), 256, 0, stream>>>(
            hn, in_proj_w + (size_t)i * 768 * DMODEL, nullptr, xz, NTOK, 768, DMODEL);
        conv_xproj_dt<<<NTOK, 256, 0, stream>>>(
            xz, conv_w + (size_t)i * DINNER * 4, conv_b + (size_t)i * DINNER,
            xproj_w + (size_t)i * 44 * DINNER, dtproj_w + (size_t)i * DINNER * DTRANK,
            dtproj_b + (size_t)i * DINNER, ubuf, dtbuf, bcbuf);
        scan_kernel<<<192, 256, 0, stream>>>(
            ubuf, dtbuf, bcbuf, xz, A_log + (size_t)i * DINNER * DSTATE,
            D_param + (size_t)i * DINNER, ybuf);
        gemm_bf16<<<dim3(25, 3), 256, 0, stream>>>(
            ybuf, outproj_w + (size_t)i * DMODEL * DINNER, nullptr, hbuf, NTOK, DMODEL, DINNER);
    }

    addln<<<NTOK, 64, 0, stream>>>(hbuf, residual, (float*)d_out,
                                   normf_w, normf_b, 1);
}